// Round 7
// baseline (229.658 us; speedup 1.0000x reference)
//
#include <hip/hip_runtime.h>
#include <hip/hip_bf16.h>
#include <math.h>

#define LHIST 50

typedef __attribute__((ext_vector_type(8))) short bf16x8;
typedef __attribute__((ext_vector_type(8))) unsigned short u16x8;
typedef __attribute__((ext_vector_type(4))) unsigned u32x4;
typedef __attribute__((ext_vector_type(4))) float f32x4;

__device__ __forceinline__ unsigned short f2bf(float f) {
    union { float f; unsigned u; } v; v.f = f;
    unsigned r = v.u + 0x7fff + ((v.u >> 16) & 1);   // RNE
    return (unsigned short)(r >> 16);
}
__device__ __forceinline__ float bf2f(unsigned short h) {
    return __builtin_bit_cast(float, (unsigned)h << 16);
}
__device__ __forceinline__ unsigned pk2(float lo, float hi) {   // v_cvt_pk_bf16_f32
    __hip_bfloat162 h = __float22bfloat162_rn(make_float2(lo, hi));
    unsigned u;
    __builtin_memcpy(&u, &h, 4);
    return u;
}
__device__ __forceinline__ f32x4 mfma16(bf16x8 a, bf16x8 b, f32x4 c) {
    return __builtin_amdgcn_mfma_f32_16x16x32_bf16(a, b, c, 0, 0, 0);
}
// hq = h (bf16) * q (bf16 packed), repacked bf16 — registers only
__device__ __forceinline__ bf16x8 mulqp(u16x8 h, u16x8 qp) {
    u32x4 r;
    r[0] = pk2(bf2f(h[0]) * bf2f(qp[0]), bf2f(h[1]) * bf2f(qp[1]));
    r[1] = pk2(bf2f(h[2]) * bf2f(qp[2]), bf2f(h[3]) * bf2f(qp[3]));
    r[2] = pk2(bf2f(h[4]) * bf2f(qp[4]), bf2f(h[5]) * bf2f(qp[5]));
    r[3] = pk2(bf2f(h[6]) * bf2f(qp[6]), bf2f(h[7]) * bf2f(qp[7]));
    return __builtin_bit_cast(bf16x8, r);
}

// ws float offsets:
//  W13fb  frag bf16 [nt5][ks2][lane][8]   @ 0         (2560 f)   (W1+W3)
//  Bmfb   frag bf16 [nt5][ks2][lane][8]   @ 5120      (2560 f)   (W2-W3)
//  W4fb   frag bf16 [nt5][ks2][lane][8]   @ 7680      (2560 f)   (W4)
//  W1f    frag bf16 [nt16][ks5][lane][8]  @ 10240     (20480 f)
//  W2f    frag bf16 [nt8][ks8][lane][8]   @ 30720     (16384 f)
//  itemb  bf16 [NI*32]                    @ 47104     (NI*16 f)
//  catb   bf16 [NC*32]                    @ 47104+NI*16
//  combined [B][160] fp32                 after catb

__global__ void prep_kernel(const float* __restrict__ aw1,
                            const float* __restrict__ mw1,
                            const float* __restrict__ mw2,
                            const float* __restrict__ item_table,
                            const float* __restrict__ cat_table,
                            int itemN, int catN,
                            unsigned short* __restrict__ W13fb,
                            unsigned short* __restrict__ Bmfb,
                            unsigned short* __restrict__ W4fb,
                            unsigned short* __restrict__ W1f,
                            unsigned short* __restrict__ W2f,
                            unsigned short* __restrict__ itemb,
                            unsigned short* __restrict__ catb) {
    int i = blockIdx.x * 256 + threadIdx.x;
    int i8 = i * 8;
    if (i8 + 7 < itemN) {
        float4 a = *(const float4*)&item_table[i8];
        float4 b = *(const float4*)&item_table[i8 + 4];
        uint4 r;
        r.x = pk2(a.x, a.y); r.y = pk2(a.z, a.w);
        r.z = pk2(b.x, b.y); r.w = pk2(b.z, b.w);
        *(uint4*)&itemb[i8] = r;
    }
    if (i8 + 7 < catN) {
        float4 a = *(const float4*)&cat_table[i8];
        float4 b = *(const float4*)&cat_table[i8 + 4];
        uint4 r;
        r.x = pk2(a.x, a.y); r.y = pk2(a.z, a.w);
        r.z = pk2(b.x, b.y); r.w = pk2(b.z, b.w);
        *(uint4*)&catb[i8] = r;
    }
    if (i < 5120) {
        int kk = i / 80, n = i - kk * 80;
        int nt = n >> 4, colw = n & 15, ks = kk >> 5, r = kk & 31, qd = r >> 3, off = r & 7;
        int d = ((nt * 2 + ks) * 64 + qd * 16 + colw) * 8 + off;
        Bmfb[d]  = f2bf(aw1[(64 + kk) * 80 + n] - aw1[(128 + kk) * 80 + n]);   // W2-W3
        W4fb[d]  = f2bf(aw1[(192 + kk) * 80 + n]);                              // W4
        W13fb[d] = f2bf(aw1[kk * 80 + n] + aw1[(128 + kk) * 80 + n]);           // W1+W3
    }
    if (i < 40960) {
        int kk = i >> 8, n = i & 255;
        int nt = n >> 4, colw = n & 15, ks = kk >> 5, r = kk & 31, qd = r >> 3, off = r & 7;
        W1f[((nt * 5 + ks) * 64 + qd * 16 + colw) * 8 + off] = f2bf(mw1[i]);
    }
    if (i < 32768) {
        int kk = i >> 7, n = i & 127;
        int nt = n >> 4, colw = n & 15, ks = kk >> 5, r = kk & 31, qd = r >> 3, off = r & 7;
        W2f[((nt * 8 + ks) * 64 + qd * 16 + colw) * 8 + off] = f2bf(mw2[i]);
    }
}

// ---------- attention: 1 batch/block, wave = l-quarter (1 l-tile/wave) ----------
// score[l][j] = relu( q.(W1+W3)[j] + h[l].(W2-W3)[:,j] + (h[l]*q).W4[:,j] + ab1[j] ) . aw2
// Fused per-jt bias+score: one f32x4 acc live at a time. Arch VGPRs < 64 -> 4 waves/SIMD.

#define JT_STEP(JT) { \
    bf16x8 w0 = *(const bf16x8*)&W13fb[((JT * 2 + 0) * 64 + lane) * 8]; \
    bf16x8 w1 = *(const bf16x8*)&W13fb[((JT * 2 + 1) * 64 + lane) * 8]; \
    f32x4 acc = (f32x4){0.f, 0.f, 0.f, 0.f}; \
    acc = mfma16(w0, __builtin_bit_cast(bf16x8, qbi), acc); \
    acc = mfma16(w1, __builtin_bit_cast(bf16x8, qbc), acc); \
    bf16x8 a23_0 = *(const bf16x8*)&Bmfb[((JT * 2 + 0) * 64 + lane) * 8]; \
    bf16x8 a23_1 = *(const bf16x8*)&Bmfb[((JT * 2 + 1) * 64 + lane) * 8]; \
    acc = mfma16(a23_0, __builtin_bit_cast(bf16x8, vi), acc); \
    acc = mfma16(a23_1, __builtin_bit_cast(bf16x8, vc), acc); \
    bf16x8 a4_0 = *(const bf16x8*)&W4fb[((JT * 2 + 0) * 64 + lane) * 8]; \
    bf16x8 a4_1 = *(const bf16x8*)&W4fb[((JT * 2 + 1) * 64 + lane) * 8]; \
    acc = mfma16(a4_0, hqi, acc); \
    acc = mfma16(a4_1, hqc, acc); \
    float4 b4 = *(const float4*)&ab1[JT * 16 + quad * 4]; \
    float4 a2 = *(const float4*)&aw2[JT * 16 + quad * 4]; \
    p += fmaxf(acc[0] + b4.x, 0.f) * a2.x + fmaxf(acc[1] + b4.y, 0.f) * a2.y \
       + fmaxf(acc[2] + b4.z, 0.f) * a2.z + fmaxf(acc[3] + b4.w, 0.f) * a2.w; }

__global__ void __launch_bounds__(256, 4) attn_kernel(
    const int* __restrict__ cid, const int* __restrict__ cg,
    const int* __restrict__ cc,  const int* __restrict__ hg,
    const int* __restrict__ hc,
    const float* __restrict__ user_table, const float* __restrict__ item_table,
    const float* __restrict__ cat_table,
    const float* __restrict__ ab1, const float* __restrict__ aw2,
    const unsigned short* __restrict__ W13fb, const unsigned short* __restrict__ Bmfb,
    const unsigned short* __restrict__ W4fb,
    const unsigned short* __restrict__ itemb, const unsigned short* __restrict__ catb,
    float* __restrict__ combined)
{
    __shared__ float red[4][1056];     // per-wave private transpose scratch
    __shared__ float sh_sc[64];        // scores
    __shared__ float sh_att[4][64];    // per-wave att partial rows

    const int t = threadIdx.x;
    const int wv = t >> 6;             // l-tile index (0..3)
    const int lane = t & 63;
    const int quad = lane >> 4;
    const int col = lane & 15;
    const int b = blockIdx.x;

    const int cgb = cg[b], ccb = cc[b];

    // ---- history index for this wave's l-tile (l = wv*16 + col) ----
    const int hb = b * LHIST;
    int l = wv * 16 + col;
    int lc = (l < LHIST) ? l : 0;
    int ig = hg[hb + lc];
    int ic = hc[hb + lc];
    bool bad = (l >= LHIST) || (ig == 0);

    // ---- h gathers (issue early) ----
    u16x8 vi = *(const u16x8*)&itemb[(size_t)ig * 32 + quad * 8];
    u16x8 vc = *(const u16x8*)&catb[(size_t)ic * 32 + quad * 8];

    // ---- q: load fp32, pack to bf16 (fp32 dies immediately) ----
    u16x8 qbi, qbc;
    {
        const float4 qia = *(const float4*)&item_table[(size_t)cgb * 32 + quad * 8];
        const float4 qib = *(const float4*)&item_table[(size_t)cgb * 32 + quad * 8 + 4];
        const float4 qca = *(const float4*)&cat_table[(size_t)ccb * 32 + quad * 8];
        const float4 qcb = *(const float4*)&cat_table[(size_t)ccb * 32 + quad * 8 + 4];
        u32x4 u, v;
        u[0] = pk2(qia.x, qia.y); u[1] = pk2(qia.z, qia.w);
        u[2] = pk2(qib.x, qib.y); u[3] = pk2(qib.z, qib.w);
        v[0] = pk2(qca.x, qca.y); v[1] = pk2(qca.z, qca.w);
        v[2] = pk2(qcb.x, qcb.y); v[3] = pk2(qcb.z, qcb.w);
        qbi = __builtin_bit_cast(u16x8, u);
        qbc = __builtin_bit_cast(u16x8, v);
    }

    // ---- hq frags (bf16 q) ----
    bf16x8 hqi = mulqp(vi, qbi);
    bf16x8 hqc = mulqp(vc, qbc);

    // ---- fused bias+score per jt: one acc live at a time ----
    float p = 0.f;
    JT_STEP(0)
    JT_STEP(1)
    JT_STEP(2)
    JT_STEP(3)
    JT_STEP(4)
    p += __shfl_xor(p, 16);
    p += __shfl_xor(p, 32);

    // ---- stage masked scores (all 64 slots covered by 4 waves x 16 cols) ----
    if (quad == 0) sh_sc[wv * 16 + col] = bad ? -1e9f : p;
    __syncthreads();

    // ---- full softmax over l (each wave redundantly) ----
    float sc = sh_sc[lane];
    float m = sc;
    m = fmaxf(m, __shfl_xor(m, 32));
    m = fmaxf(m, __shfl_xor(m, 16));
    m = fmaxf(m, __shfl_xor(m, 8));
    m = fmaxf(m, __shfl_xor(m, 4));
    m = fmaxf(m, __shfl_xor(m, 2));
    m = fmaxf(m, __shfl_xor(m, 1));
    float e = __expf(sc - m);          // masked lanes: exp(-1e9 - m) = 0
    float ssum = e;
    ssum += __shfl_xor(ssum, 32);
    ssum += __shfl_xor(ssum, 16);
    ssum += __shfl_xor(ssum, 8);
    ssum += __shfl_xor(ssum, 4);
    ssum += __shfl_xor(ssum, 2);
    ssum += __shfl_xor(ssum, 1);
    float w = e / ssum;

    // ---- weight for this lane's l ----
    float wl = __shfl(w, wv * 16 + col);

    // ---- att partials (d = quad*8 + j), single tile: direct mul ----
    float* myrow = &red[wv][col * 66];
    *(float2*)&myrow[quad * 8 + 0] = make_float2(wl * bf2f(vi[0]), wl * bf2f(vi[1]));
    *(float2*)&myrow[quad * 8 + 2] = make_float2(wl * bf2f(vi[2]), wl * bf2f(vi[3]));
    *(float2*)&myrow[quad * 8 + 4] = make_float2(wl * bf2f(vi[4]), wl * bf2f(vi[5]));
    *(float2*)&myrow[quad * 8 + 6] = make_float2(wl * bf2f(vi[6]), wl * bf2f(vi[7]));
    *(float2*)&myrow[33 + quad * 8 + 0] = make_float2(wl * bf2f(vc[0]), wl * bf2f(vc[1]));
    *(float2*)&myrow[33 + quad * 8 + 2] = make_float2(wl * bf2f(vc[2]), wl * bf2f(vc[3]));
    *(float2*)&myrow[33 + quad * 8 + 4] = make_float2(wl * bf2f(vc[4]), wl * bf2f(vc[5]));
    *(float2*)&myrow[33 + quad * 8 + 6] = make_float2(wl * bf2f(vc[6]), wl * bf2f(vc[7]));
    int colIdx = (lane < 32) ? lane : 33 + (lane - 32);
    float s = 0.f;
    #pragma unroll
    for (int c = 0; c < 16; ++c) s += red[wv][c * 66 + colIdx];
    sh_att[wv][lane] = s;
    __syncthreads();

    // ---- write combined [user | cand_item | cand_cat | att], split across waves ----
    float* crow = combined + (size_t)b * 160;
    if (wv == 0) {
        const int cidb = cid[b];
        crow[lane] = (lane < 32) ? user_table[(size_t)cidb * 32 + lane]
                                 : item_table[(size_t)cgb * 32 + (lane - 32)];
    } else if (wv == 1) {
        if (lane < 32) crow[64 + lane] = cat_table[(size_t)ccb * 32 + lane];
    } else if (wv == 2) {
        crow[96 + lane] = sh_att[0][lane] + sh_att[1][lane]
                        + sh_att[2][lane] + sh_att[3][lane];
    }
}

// ---------- MLP: MFMA, 32 batch rows per 256-thread block (unchanged) ----------
__global__ void __launch_bounds__(256, 4) mlp_kernel(
    const float* __restrict__ combined,
    const unsigned short* __restrict__ W1f, const unsigned short* __restrict__ W2f,
    const float* __restrict__ mb1, const float* __restrict__ mb2,
    const float* __restrict__ mw3, const float* __restrict__ mb3,
    float* __restrict__ out)
{
    __shared__ __align__(16) unsigned short shA1[5120];   // [mt2][ks5][lane][8]
    __shared__ __align__(16) unsigned short shA2[8192];   // [mt2][ks8][lane][8]
    __shared__ float sh_part[4][32];

    const int t = threadIdx.x;
    const int b0 = blockIdx.x * 32;
    const int wv = t >> 6;
    const int lane = t & 63;
    const int quad = lane >> 4;
    const int col = lane & 15;

    for (int i = t; i < 1280; i += 256) {
        int m = i / 40;
        int s = i - m * 40;
        int k0 = s * 4;
        float4 v = *(const float4*)&combined[(size_t)(b0 + m) * 160 + k0];
        int mt = m >> 4, colm = m & 15;
        int ks = k0 >> 5, qd = (k0 >> 3) & 3, off = k0 & 7;
        ushort4 r; r.x = f2bf(v.x); r.y = f2bf(v.y); r.z = f2bf(v.z); r.w = f2bf(v.w);
        *(ushort4*)&shA1[((mt * 5 + ks) * 64 + qd * 16 + colm) * 8 + off] = r;
    }
    __syncthreads();

    f32x4 acc1[2][4];
    #pragma unroll
    for (int mt = 0; mt < 2; ++mt)
        #pragma unroll
        for (int j = 0; j < 4; ++j) acc1[mt][j] = (f32x4){0.f, 0.f, 0.f, 0.f};
    #pragma unroll
    for (int ks = 0; ks < 5; ++ks) {
        bf16x8 a0 = *(const bf16x8*)&shA1[(ks * 64 + lane) * 8];
        bf16x8 a1 = *(const bf16x8*)&shA1[((5 + ks) * 64 + lane) * 8];
        #pragma unroll
        for (int j = 0; j < 4; ++j) {
            int ntg = wv * 4 + j;
            bf16x8 bw = *(const bf16x8*)&W1f[((ntg * 5 + ks) * 64 + lane) * 8];
            acc1[0][j] = __builtin_amdgcn_mfma_f32_16x16x32_bf16(a0, bw, acc1[0][j], 0, 0, 0);
            acc1[1][j] = __builtin_amdgcn_mfma_f32_16x16x32_bf16(a1, bw, acc1[1][j], 0, 0, 0);
        }
    }
    #pragma unroll
    for (int j = 0; j < 4; ++j) {
        int n = (wv * 4 + j) * 16 + col;
        float bj = mb1[n];
        int ks2 = n >> 5, qd2 = (n >> 3) & 3, off2 = n & 7;
        #pragma unroll
        for (int mt = 0; mt < 2; ++mt)
            #pragma unroll
            for (int i = 0; i < 4; ++i) {
                float z = fmaxf(acc1[mt][j][i] + bj, 0.f);
                shA2[((mt * 8 + ks2) * 64 + qd2 * 16 + quad * 4 + i) * 8 + off2] = f2bf(z);
            }
    }
    __syncthreads();

    f32x4 acc2[2][2];
    #pragma unroll
    for (int mt = 0; mt < 2; ++mt)
        #pragma unroll
        for (int jj = 0; jj < 2; ++jj) acc2[mt][jj] = (f32x4){0.f, 0.f, 0.f, 0.f};
    #pragma unroll
    for (int ks = 0; ks < 8; ++ks) {
        bf16x8 a0 = *(const bf16x8*)&shA2[(ks * 64 + lane) * 8];
        bf16x8 a1 = *(const bf16x8*)&shA2[((8 + ks) * 64 + lane) * 8];
        #pragma unroll
        for (int jj = 0; jj < 2; ++jj) {
            int ntg = wv * 2 + jj;
            bf16x8 bw = *(const bf16x8*)&W2f[((ntg * 8 + ks) * 64 + lane) * 8];
            acc2[0][jj] = __builtin_amdgcn_mfma_f32_16x16x32_bf16(a0, bw, acc2[0][jj], 0, 0, 0);
            acc2[1][jj] = __builtin_amdgcn_mfma_f32_16x16x32_bf16(a1, bw, acc2[1][jj], 0, 0, 0);
        }
    }
    #pragma unroll
    for (int mt = 0; mt < 2; ++mt) {
        #pragma unroll
        for (int i = 0; i < 4; ++i) {
            float p = 0.f;
            #pragma unroll
            for (int jj = 0; jj < 2; ++jj) {
                int n = (wv * 2 + jj) * 16 + col;
                float z = fmaxf(acc2[mt][jj][i] + mb2[n], 0.f);
                p += z * mw3[n];
            }
            p += __shfl_xor(p, 1);
            p += __shfl_xor(p, 2);
            p += __shfl_xor(p, 4);
            p += __shfl_xor(p, 8);
            if (col == 0) sh_part[wv][mt * 16 + quad * 4 + i] = p;
        }
    }
    __syncthreads();
    if (t < 32)
        out[b0 + t] = sh_part[0][t] + sh_part[1][t] + sh_part[2][t] + sh_part[3][t] + mb3[0];
}

extern "C" void kernel_launch(void* const* d_in, const int* in_sizes, int n_in,
                              void* d_out, int out_size, void* d_ws, size_t ws_size,
                              hipStream_t stream) {
    const int*   cid = (const int*)d_in[0];
    const int*   cg  = (const int*)d_in[1];
    const int*   cc  = (const int*)d_in[2];
    const int*   hg  = (const int*)d_in[3];
    const int*   hc  = (const int*)d_in[4];
    const float* user_table = (const float*)d_in[5];
    const float* item_table = (const float*)d_in[6];
    const float* cat_table  = (const float*)d_in[7];
    const float* aw1 = (const float*)d_in[8];
    const float* ab1 = (const float*)d_in[9];
    const float* aw2 = (const float*)d_in[10];
    const float* mw1 = (const float*)d_in[12];
    const float* mb1 = (const float*)d_in[13];
    const float* mw2 = (const float*)d_in[14];
    const float* mb2 = (const float*)d_in[15];
    const float* mw3 = (const float*)d_in[16];
    const float* mb3 = (const float*)d_in[17];
    float* out = (float*)d_out;

    const int B = in_sizes[0];                    // 16384
    const int itemN = in_sizes[6];                // NI*32
    const int catN  = in_sizes[7];                // NC*32
    float* ws = (float*)d_ws;
    unsigned short* W13fb = (unsigned short*)ws;
    unsigned short* Bmfb = (unsigned short*)(ws + 5120);
    unsigned short* W4fb = (unsigned short*)(ws + 7680);
    unsigned short* W1f  = (unsigned short*)(ws + 10240);
    unsigned short* W2f  = (unsigned short*)(ws + 30720);
    unsigned short* itemb = (unsigned short*)(ws + 47104);
    unsigned short* catb  = itemb + itemN;
    float* combined = ws + 47104 + (itemN + catN + 1) / 2;

    int n8 = (itemN + 7) / 8;
    int prep_grid = (n8 + 255) / 256;
    if (prep_grid < 160) prep_grid = 160;
    prep_kernel<<<prep_grid, 256, 0, stream>>>(aw1, mw1, mw2, item_table, cat_table,
                                               itemN, catN, W13fb, Bmfb, W4fb, W1f, W2f,
                                               itemb, catb);
    attn_kernel<<<B, 256, 0, stream>>>(cid, cg, cc, hg, hc,
                                       user_table, item_table, cat_table,
                                       ab1, aw2, W13fb, Bmfb, W4fb, itemb, catb, combined);
    mlp_kernel<<<B / 32, 256, 0, stream>>>(combined, W1f, W2f,
                                           mb1, mb2, mw3, mb3, out);
}